// Round 1
// 70.286 us; speedup vs baseline: 1.4067x; 1.4067x over previous
//
#include <hip/hip_runtime.h>

#define STEP 10
#define NCH  256                 // 128*2 flattened channels = DP "batches"
#define CSCL (-144.2695041f)     // -(1/GAMMA)*log2(e): scale into log2 domain
#define GLN2 (-0.00693147181f)   // -GAMMA*ln(2) == 1/CSCL (to 7e-10 rel)
#define BIGP (-1.442695041e12f)  // 1e10 * CSCL : boundary "BIG" in scaled domain
#define YOFF 252                 // pad so idx = (s-2-4l) + YOFF >= 0, 16B-aligned
#define YLDS 768                 // covers YOFF + 2N + 4 for N <= 256

// exp2/log2 via raw ISA (no fast-math dependence)
__device__ __forceinline__ float fexp2(float x){ float r; asm("v_exp_f32 %0, %1" : "=v"(r) : "v"(x)); return r; }
__device__ __forceinline__ float flog2(float x){ float r; asm("v_log_f32 %0, %1" : "=v"(r) : "v"(x)); return r; }

// One soft-DTW cell in the scaled domain R' = R*CSCL (CSCL < 0):
//   softmin folds to: R'new = d^2*CSCL + log2(1 + 2^(lo-m) + 2^(mid-m)) + m
// because CSCL*GLN2 == 1 exactly (mathematically), and the max term is 2^0 = 1.
__device__ __forceinline__ float dpcell(float up2, float up, float left,
                                        float xv, float yv, int jj, unsigned nlim) {
    float m  = fmaxf(fmaxf(up2, up), left);            // v_max3_f32
    float lo = fminf(fminf(up2, up), left);            // v_min3_f32
    float md = __builtin_amdgcn_fmed3f(up2, up, left); // v_med3_f32
    float e  = fexp2(lo - m) + fexp2(md - m) + 1.0f;
    float ls = flog2(e) + m;
    float d  = xv - yv;
    float v  = fmaf(d * CSCL, d, ls);
    return ((unsigned)jj < nlim) ? v : BIGP;           // j in [1,N] && row valid
}

// One wave (64 lanes) per batch. Lane l owns rows i0..i0+3 (i0 = 4l+1).
// DP state entirely in registers, carried in the *scaled* domain.
// Anti-diagonal wavefront; ONE ds_bpermute per diagonal (issued 3 cells early),
// bq re-uses the previous diagonal's bp, y comes from a padded LDS array via
// one ds_read_b128 per 4 diagonals (index == jm1; OOB pads are masked cells).
__global__ __launch_bounds__(64)
void softdtw_wave(const float* __restrict__ x, const float* __restrict__ y,
                  float* __restrict__ ws, int N) {
    const int b = blockIdx.x;
    const int l = threadIdx.x;
    const bool l0 = (l == 0);

    __shared__ __align__(16) float YsP[YLDS];
    for (int j = l; j < YLDS; j += 64) YsP[j] = 0.0f;
    __syncthreads();
    for (int j = l; j < N; j += 64) YsP[YOFF + j] = y[j * STEP * NCH + b];
    __syncthreads();

    const int i0 = 4 * l + 1;   // first row owned by this lane
    float xv0 = (i0     <= N) ? x[(i0 - 1) * STEP * NCH + b] : 0.f;
    float xv1 = (i0 + 1 <= N) ? x[(i0    ) * STEP * NCH + b] : 0.f;
    float xv2 = (i0 + 2 <= N) ? x[(i0 + 1) * STEP * NCH + b] : 0.f;
    float xv3 = (i0 + 3 <= N) ? x[(i0 + 2) * STEP * NCH + b] : 0.f;
    const unsigned nl0 = (i0     <= N) ? (unsigned)N : 0u;
    const unsigned nl1 = (i0 + 1 <= N) ? (unsigned)N : 0u;
    const unsigned nl2 = (i0 + 2 <= N) ? (unsigned)N : 0u;
    const unsigned nl3 = (i0 + 3 <= N) ? (unsigned)N : 0u;

    // scaled DP state: sp* = diag s-1, sq* = diag s-2 (sq3 never needed)
    float sp0 = BIGP, sp1 = BIGP, sp2 = BIGP, sp3 = BIGP;
    float sq0 = BIGP, sq1 = BIGP, sq2 = BIGP;
    // neighbor-row (i0-1) values: bp = diag s-1, bq = diag s-2.
    // bq(s) == bp(s-1) algebraically, so only ONE shuffle per diagonal.
    float bp = BIGP;
    float bq = l0 ? 0.0f : BIGP;      // R'[0][0] = 0 enters at s=2
    // y window: w0 = Ys[jm1], w1..w3 = older (only read where cell valid)
    float w0 = 0.f, w1 = 0.f, w2 = 0.f, w3 = 0.f;

    int jm1 = -4 * l;                 // (j-1) for r=0 at s=2
    const int smax = 2 * N;

    // lane-relative float4 pointer into the padded y array (16B aligned)
    const float4* yp4 = (const float4*)(YsP + YOFF) - l;
    float4 yb = yp4[0];               // y values for diagonals s=2..5

    // rotate y window, compute c3 first, launch its shuffle, then c0..c2.
    #define DSTEP(WNEW, JC) do {                                          \
        w3 = w2; w2 = w1; w1 = w0; w0 = (WNEW);                           \
        float c3  = dpcell(sq2, sp2, sp3, xv3, w3, (JC) - 3, nl3);        \
        float bpn = __shfl_up(c3, 1, 64);                                 \
        float c0  = dpcell(bq,  bp,  sp0, xv0, w0, (JC),     nl0);        \
        float c1  = dpcell(sq0, sp0, sp1, xv1, w1, (JC) - 1, nl1);        \
        float c2  = dpcell(sq1, sp1, sp2, xv2, w2, (JC) - 2, nl2);        \
        sq0 = sp0; sq1 = sp1; sq2 = sp2;                                  \
        sp0 = c0;  sp1 = c1;  sp2 = c2;  sp3 = c3;                        \
        bq = bp;  bp = l0 ? BIGP : bpn;                                   \
    } while (0)

    int s = 2, g = 0;
    for (; s + 3 <= smax; s += 4, ++g) {
        float4 ybn = yp4[g + 1];      // prefetch next 4 diagonals' y values
        DSTEP(yb.x, jm1);
        DSTEP(yb.y, jm1 + 1);
        DSTEP(yb.z, jm1 + 2);
        DSTEP(yb.w, jm1 + 3);
        yb = ybn;
        jm1 += 4;
    }
    // tail: at most 3 diagonals, y already prefetched in yb
    if (s     <= smax) DSTEP(yb.x, jm1);
    if (s + 1 <= smax) DSTEP(yb.y, jm1 + 1);
    if (s + 2 <= smax) DSTEP(yb.z, jm1 + 2);
    #undef DSTEP

    // R[N][N] sits on diag 2N at row N = i0 + r; un-scale on the way out
    if      (i0     == N) ws[b] = sp0 * GLN2;
    else if (i0 + 1 == N) ws[b] = sp1 * GLN2;
    else if (i0 + 2 == N) ws[b] = sp2 * GLN2;
    else if (i0 + 3 == N) ws[b] = sp3 * GLN2;
}

// Deterministic 256 -> 1 reduction (shuffle within wave64, LDS across 4 waves)
__global__ __launch_bounds__(256)
void reduce256(const float* __restrict__ ws, float* __restrict__ out) {
    const int tid = threadIdx.x;
    float v = ws[tid];
    #pragma unroll
    for (int off = 32; off > 0; off >>= 1)
        v += __shfl_down(v, off, 64);
    __shared__ float partial[4];
    if ((tid & 63) == 0) partial[tid >> 6] = v;
    __syncthreads();
    if (tid == 0) out[0] = (partial[0] + partial[1]) + (partial[2] + partial[3]);
}

extern "C" void kernel_launch(void* const* d_in, const int* in_sizes, int n_in,
                              void* d_out, int out_size, void* d_ws, size_t ws_size,
                              hipStream_t stream) {
    const float* x = (const float*)d_in[0];
    const float* y = (const float*)d_in[1];
    float* out = (float*)d_out;
    float* ws  = (float*)d_ws;

    const int T = in_sizes[0] / NCH;            // 2048 frames
    const int L = (T + STEP - 1) / STEP;        // 205 subsampled frames

    softdtw_wave<<<dim3(NCH), dim3(64), 0, stream>>>(x, y, ws, L);
    reduce256<<<dim3(1), dim3(256), 0, stream>>>(ws, out);
}